// Round 3
// baseline (443.042 us; speedup 1.0000x reference)
//
#include <hip/hip_runtime.h>
#include <stdint.h>

typedef unsigned long long u64;
typedef unsigned int u32;

// ---------------------------------------------------------------------------
// Constants: 17 feats/row, beta = col 9, cc = cols 14..16, T_B=0.85, T_D^2=0.09.
// Greedy condensation == scan candidates in descending (betaBits, ~idx) key
// order, accept iff not within T_D of any previously accepted center.
// R2: batched multi-pick greedy (horizon-bounded exact batch per pass) +
// single-pass filter. Replaces 42 one-pick passes with ~3-4 passes.
// ---------------------------------------------------------------------------

__global__ void init_kernel(int* segCount, int* condCount, int nseg) {
    int t = threadIdx.x;
    if (t < nseg) { segCount[t] = 0; condCount[t] = 0; }
}

// Single-pass filter: block-local LDS staging, ONE global atomic per block
// (256 contenders on 4 counters). Within-segment order is nondeterministic,
// but the greedy uses exact keys and output is sorted -> deterministic output.
__launch_bounds__(256)
__global__ void filter_kernel(const float* __restrict__ x, int S, int chunk, int bps,
                              int* __restrict__ segCount,
                              float4* __restrict__ A, int* __restrict__ iA, int CAP) {
    __shared__ float4 stg[1024];
    __shared__ int sgi[1024];
    __shared__ int s_cnt, s_base;
    int b = blockIdx.x;
    int s = b / bps, c = b % bps;
    int start = s * S + c * chunk;
    int end = min(start + chunk, s * S + S);
    if (threadIdx.x == 0) s_cnt = 0;
    __syncthreads();
    for (int i = start + threadIdx.x; i < end; i += 256) {
        float beta = x[(size_t)i * 17 + 9];
        if (beta >= 0.85f) {
            int p = atomicAdd(&s_cnt, 1);
            if (p < 1024) {
                stg[p] = make_float4(x[(size_t)i * 17 + 14], x[(size_t)i * 17 + 15],
                                     x[(size_t)i * 17 + 16], beta);
                sgi[p] = i;
            }
        }
    }
    __syncthreads();
    if (threadIdx.x == 0) s_base = atomicAdd(&segCount[s], min(s_cnt, 1024));
    __syncthreads();
    int cnt = min(s_cnt, 1024);
    for (int k = threadIdx.x; k < cnt; k += 256) {
        int pos = s_base + k;
        if (pos < CAP) {
            A[(size_t)s * CAP + pos] = stg[k];
            iA[(size_t)s * CAP + pos] = sgi[k];
        }
    }
}

// One block (1024 thr) per segment. Per pass:
//  scan:  update per-thread u64 alive mask vs last pass's new centers,
//         keep per-thread top-2 keys (+coords for top-1)
//  rank:  per-wave top-8 sorted list via 64-iter rank selection;
//         horizon H = max(all thread 2nd-bests, all wave 9th-bests)
//  pop:   wave 0 merge-pops the 16 sorted lists in exact desc order while
//         key > H; in-batch coverage in registers (lane i = center i) -> exact
//         greedy prefix committed in one pass (~49 picks expected).
__launch_bounds__(1024)
__global__ void greedy_kernel(const float4* __restrict__ A, const int* __restrict__ iA,
                              const int* __restrict__ candCount, int CAP,
                              int* __restrict__ condList, int* __restrict__ condCount,
                              int CCAP) {
    const int s = blockIdx.x;
    const int tid = threadIdx.x;
    const int lane = tid & 63;
    const int wid = tid >> 6;

    __shared__ u64 sKey[16][8];
    __shared__ float sX[16][8], sY[16][8], sZ[16][8];
    __shared__ float ctrX[2048], ctrY[2048], ctrZ[2048];
    __shared__ int ctrGi[2048];
    __shared__ u64 s_H;
    __shared__ int s_alive, s_nacc;

    const float4* cand = A + (size_t)s * CAP;
    const int* gi = iA + (size_t)s * CAP;
    int n = candCount[s]; if (n > CAP) n = CAP;

    u64 alive = ~0ull;            // bit t = candidate j = tid + (t<<10)
    int condTotal = 0, prevStart = 0;
    int passes = 0;

    while (true) {
        if (tid == 0) { s_H = 0; s_alive = 0; s_nacc = 0; }
        if (lane < 8) sKey[wid][lane] = 0;   // wave-private: no barrier needed
        __syncthreads();

        // ---- scan ----
        u64 k1 = 0, k2 = 0;
        float bx = 0.f, by = 0.f, bz = 0.f;
        int myAlive = 0;
        for (int t = 0;; ++t) {
            int j = tid + (t << 10);
            if (j >= n) break;
            if (!((alive >> t) & 1ull)) continue;
            float4 c = cand[j];
            bool cov = false;
            for (int m = prevStart; m < condTotal; ++m) {
                float dx = __fsub_rn(c.x, ctrX[m]);
                float dy = __fsub_rn(c.y, ctrY[m]);
                float dz = __fsub_rn(c.z, ctrZ[m]);
                float dsq = __fadd_rn(__fadd_rn(__fmul_rn(dx, dx), __fmul_rn(dy, dy)),
                                      __fmul_rn(dz, dz));
                if (dsq < 0.09f) { cov = true; break; }
            }
            if (cov) { alive &= ~(1ull << t); continue; }
            myAlive++;
            u32 bb = __float_as_uint(c.w);
            u64 key = ((u64)bb << 32) | (u64)(0xFFFFFFFFu - (u32)gi[j]);
            if (key > k1) { k2 = k1; k1 = key; bx = c.x; by = c.y; bz = c.z; }
            else if (key > k2) k2 = key;
        }
        int asum = myAlive; u64 m2 = k2;
        for (int off = 32; off > 0; off >>= 1) {
            asum += __shfl_down(asum, off);
            u64 o = __shfl_down(m2, off);
            if (o > m2) m2 = o;
        }
        if (lane == 0) { atomicAdd(&s_alive, asum); atomicMax(&s_H, m2); }
        __syncthreads();
        if (s_alive == 0) break;

        // ---- per-wave rank selection (keys unique except zeros) ----
        int rank = 0;
        for (int i2 = 0; i2 < 64; ++i2) {
            u64 kk = __shfl(k1, i2);
            rank += (kk > k1) ? 1 : 0;
        }
        if (rank < 8 && k1 != 0) {
            sKey[wid][rank] = k1; sX[wid][rank] = bx; sY[wid][rank] = by; sZ[wid][rank] = bz;
        }
        if (rank == 8) atomicMax(&s_H, k1);
        __syncthreads();

        // ---- pop (wave 0) ----
        if (wid == 0) {
            u64 H = s_H;
            int head = (lane < 16) ? 0 : 8;
            float ax = 0.f, ay = 0.f, az = 0.f; int agi2 = 0;
            int nacc = 0;
            while (nacc < 64) {
                u64 bk = (head < 8) ? sKey[lane][head] : 0;
                int src = lane;
                for (int off = 32; off > 0; off >>= 1) {
                    u64 ok = __shfl_xor(bk, off);
                    int oi = __shfl_xor(src, off);
                    if (ok > bk) { bk = ok; src = oi; }
                }
                if (bk <= H) break;
                int L = src;                        // uniform
                int hL = __shfl(head, L);           // uniform
                float wx = sX[L][hL], wy = sY[L][hL], wz = sZ[L][hL];
                u32 wgi = 0xFFFFFFFFu - (u32)(bk & 0xFFFFFFFFull);
                if (lane == L) head++;
                bool cov = false;
                if (lane < nacc) {
                    float dx = __fsub_rn(wx, ax);
                    float dy = __fsub_rn(wy, ay);
                    float dz = __fsub_rn(wz, az);
                    float dsq = __fadd_rn(__fadd_rn(__fmul_rn(dx, dx), __fmul_rn(dy, dy)),
                                          __fmul_rn(dz, dz));
                    cov = dsq < 0.09f;
                }
                if (__ballot(cov) == 0ull) {
                    if (lane == nacc) { ax = wx; ay = wy; az = wz; agi2 = (int)wgi; }
                    nacc++;
                }
            }
            if (lane < nacc && condTotal + lane < 2048) {
                ctrX[condTotal + lane] = ax; ctrY[condTotal + lane] = ay;
                ctrZ[condTotal + lane] = az; ctrGi[condTotal + lane] = agi2;
            }
            if (lane == 0) s_nacc = nacc;
        }
        __syncthreads();
        prevStart = condTotal;
        condTotal += s_nacc;
        if (condTotal > 2048) condTotal = 2048;
        __syncthreads();   // s_nacc / sKey reuse + ctr visibility for next scan
        if (condTotal >= 2048 || ++passes > 256) break;  // safety (never expected)
    }

    for (int i = tid; i < condTotal; i += 1024)
        condList[(size_t)s * CCAP + i] = ctrGi[i];
    if (tid == 0) condCount[s] = condTotal;
}

// Rank-sort each segment's pick list ascending (tiny), global sorted order,
// ncond cumulative counts as float32.
__global__ void finalize_kernel(const int* __restrict__ condList,
                                const int* __restrict__ condCount, int CCAP,
                                int* __restrict__ sorted, int* __restrict__ prefix,
                                float* __restrict__ ncond_out, int nseg, int rows) {
    __shared__ int lst[2048];
    __shared__ int pfx[9];
    int tid = threadIdx.x;
    if (tid == 0) {
        int acc = 0; pfx[0] = 0;
        for (int s2 = 0; s2 < nseg; s2++) { acc += condCount[s2]; pfx[s2 + 1] = acc; }
    }
    __syncthreads();
    if (tid <= nseg) { prefix[tid] = pfx[tid]; ncond_out[tid] = (float)pfx[tid]; }
    for (int s2 = 0; s2 < nseg; s2++) {
        int ns = condCount[s2]; if (ns > CCAP) ns = CCAP;
        for (int i = tid; i < ns; i += blockDim.x) lst[i] = condList[(size_t)s2 * CCAP + i];
        __syncthreads();
        for (int i = tid; i < ns; i += blockDim.x) {
            int v = lst[i]; int rank = 0;
            for (int j = 0; j < ns; j++) rank += (lst[j] < v);
            int pos = pfx[s2] + rank;
            if (pos < rows) sorted[pos] = v;
        }
        __syncthreads();
    }
}

__global__ void emit_kernel(const float* __restrict__ x, const int* __restrict__ sorted,
                            const int* __restrict__ prefix, float* __restrict__ out,
                            int rows, int nseg) {
    int e = blockIdx.x * blockDim.x + threadIdx.x;
    if (e >= rows * 17) return;
    int total = prefix[nseg];
    int j = e / 17, k = e - j * 17;
    float v = 0.f;
    if (j < total) v = x[(size_t)sorted[j] * 17 + k];
    out[e] = v;
}

extern "C" void kernel_launch(void* const* d_in, const int* in_sizes, int n_in,
                              void* d_out, int out_size, void* d_ws, size_t ws_size,
                              hipStream_t stream) {
    const float* x = (const float*)d_in[0];
    const int nseg = in_sizes[1] - 1;          // 4
    const int N = in_sizes[0] / 17;            // 1,000,000
    const int S = N / nseg;                    // 250,000
    const int rows = (out_size - (nseg + 1)) / 17;  // 1024 (MAX_COND)
    const int CCAP = 2048;

    const int bps = 1024 / nseg;               // blocks per segment (256)
    const int nBlocks = nseg * bps;            // 1024
    const int chunk = (S + bps - 1) / bps;     // 977 (< 1024 LDS staging cap)

    // workspace: [A float4][iA][condList][segCount][condCount][sorted][prefix]
    char* w = (char*)d_ws;
    size_t fixedBytes = (size_t)nseg * CCAP * 4 + (size_t)nseg * 4 * 2 +
                        (size_t)rows * 4 + (size_t)(nseg + 1) * 4 + 4096;
    size_t perCand = (size_t)nseg * (16 + 4);
    size_t avail = (ws_size > fixedBytes) ? (ws_size - fixedBytes) : 0;
    int CAP = (int)(avail / perCand);
    if (CAP > 65536) CAP = 65536;   // also = 64-bit alive mask limit (64*1024)
    if (CAP < 1) CAP = 1;

    float4* A = (float4*)w;
    int* iA = (int*)(A + (size_t)nseg * CAP);
    int* condList  = iA + (size_t)nseg * CAP;
    int* segCount  = condList + (size_t)nseg * CCAP;
    int* condCount = segCount + nseg;
    int* sorted    = condCount + nseg;
    int* prefix    = sorted + rows;
    float* out = (float*)d_out;

    init_kernel<<<1, 64, 0, stream>>>(segCount, condCount, nseg);
    filter_kernel<<<nBlocks, 256, 0, stream>>>(x, S, chunk, bps, segCount, A, iA, CAP);
    greedy_kernel<<<nseg, 1024, 0, stream>>>(A, iA, segCount, CAP,
                                             condList, condCount, CCAP);
    finalize_kernel<<<1, 256, 0, stream>>>(condList, condCount, CCAP, sorted, prefix,
                                           out + (size_t)rows * 17, nseg, rows);
    emit_kernel<<<(rows * 17 + 255) / 256, 256, 0, stream>>>(x, sorted, prefix, out,
                                                             rows, nseg);
}

// Round 4
// 393.014 us; speedup vs baseline: 1.1273x; 1.1273x over previous
//
#include <hip/hip_runtime.h>
#include <stdint.h>

typedef unsigned long long u64;
typedef unsigned int u32;

// ---------------------------------------------------------------------------
// Constants: 17 feats/row, beta = col 9, cc = cols 14..16, T_B=0.85, T_D^2=0.09.
// Greedy condensation == scan candidates in descending (betaBits, ~idx) key
// order, accept iff not within T_D of any previously accepted center.
// R4: deep horizon (thread top-5 + wave sorted top-16 extraction) so pass 1
// commits ~all picks, + compaction (R2) so later passes shrink. R3's shallow
// top-2 horizon committed few picks/pass over full 37.5k rescans -> 429us.
// ---------------------------------------------------------------------------

__global__ void init_kernel(int* segCount, int* condCount, int nseg) {
    int t = threadIdx.x;
    if (t < nseg) { segCount[t] = 0; condCount[t] = 0; }
}

// Single-pass filter: block-local LDS staging, ONE global atomic per block.
__launch_bounds__(256)
__global__ void filter_kernel(const float* __restrict__ x, int S, int chunk, int bps,
                              int* __restrict__ segCount,
                              float4* __restrict__ A, int* __restrict__ iA, int CAP) {
    __shared__ float4 stg[1024];
    __shared__ int sgi[1024];
    __shared__ int s_cnt, s_base;
    int b = blockIdx.x;
    int s = b / bps, c = b % bps;
    int start = s * S + c * chunk;
    int end = min(start + chunk, s * S + S);
    if (threadIdx.x == 0) s_cnt = 0;
    __syncthreads();
    for (int i = start + threadIdx.x; i < end; i += 256) {
        float beta = x[(size_t)i * 17 + 9];
        if (beta >= 0.85f) {
            int p = atomicAdd(&s_cnt, 1);
            if (p < 1024) {
                stg[p] = make_float4(x[(size_t)i * 17 + 14], x[(size_t)i * 17 + 15],
                                     x[(size_t)i * 17 + 16], beta);
                sgi[p] = i;
            }
        }
    }
    __syncthreads();
    if (threadIdx.x == 0) s_base = atomicAdd(&segCount[s], min(s_cnt, 1024));
    __syncthreads();
    int cnt = min(s_cnt, 1024);
    for (int k = threadIdx.x; k < cnt; k += 256) {
        int pos = s_base + k;
        if (pos < CAP) {
            A[(size_t)s * CAP + pos] = stg[k];
            iA[(size_t)s * CAP + pos] = sgi[k];
        }
    }
}

// One block (1024 thr) per segment.
__launch_bounds__(1024)
__global__ void greedy_kernel(float4* __restrict__ A, int* __restrict__ iA,
                              float4* __restrict__ Bb, int* __restrict__ iB,
                              const int* __restrict__ candCount, int CAP,
                              int* __restrict__ condList, int* __restrict__ condCount,
                              int CCAP) {
    const int s = blockIdx.x;
    const int tid = threadIdx.x;
    const int lane = tid & 63;
    const int wid = tid >> 6;

    __shared__ u64 sKey[16][16];
    __shared__ float4 sCtr[16][16];
    __shared__ float4 ctr[1024];
    __shared__ int ctrGi[1024];
    __shared__ u64 s_H;
    __shared__ int s_newN, s_nacc;

    float4* cur = A + (size_t)s * CAP;
    int*    icur = iA + (size_t)s * CAP;
    float4* nxt = Bb + (size_t)s * CAP;
    int*    inxt = iB + (size_t)s * CAP;
    int n = candCount[s]; if (n > CAP) n = CAP;

    int condTotal = 0, prevStart = 0, passes = 0;

    while (true) {
        if (tid == 0) { s_H = 0; s_newN = 0; s_nacc = 0; }
        __syncthreads();

        const bool first = (condTotal == 0);

        // ---- scan: coverage vs last pass's centers, compact, thread top-5 ----
        u64 k1_=0,k2_=0,k3_=0,k4_=0,k5_=0;
        float x1_=0,y1_=0,z1_=0,x2_=0,y2_=0,z2_=0,
              x3_=0,y3_=0,z3_=0,x4_=0,y4_=0,z4_=0;
        for (int j = tid; j < n; j += 1024) {
            float4 c = cur[j];
            int g = icur[j];
            bool live = true;
            if (!first) {
                for (int m = prevStart; m < condTotal; ++m) {
                    float4 cc = ctr[m];   // uniform m -> LDS broadcast
                    float dx = __fsub_rn(c.x, cc.x);
                    float dy = __fsub_rn(c.y, cc.y);
                    float dz = __fsub_rn(c.z, cc.z);
                    float dsq = __fadd_rn(__fadd_rn(__fmul_rn(dx,dx), __fmul_rn(dy,dy)),
                                          __fmul_rn(dz,dz));
                    if (dsq < 0.09f) { live = false; break; }
                }
            }
            u64 bal = __ballot(live);
            if (live) {
                if (!first) {   // pass 1: everything survives, skip the copy
                    int leader = __ffsll((unsigned long long)bal) - 1;
                    int base = 0;
                    if (lane == leader) base = atomicAdd(&s_newN, __popcll(bal));
                    base = __shfl(base, leader);
                    int off = __popcll(bal & ((1ull << lane) - 1ull));
                    nxt[base + off] = c;
                    inxt[base + off] = g;
                }
                u64 key = ((u64)__float_as_uint(c.w) << 32) | (u64)(0xFFFFFFFFu - (u32)g);
                if (key > k5_) {
                    if (key > k4_) {
                        k5_ = k4_;
                        if (key > k3_) {
                            k4_=k3_; x4_=x3_; y4_=y3_; z4_=z3_;
                            if (key > k2_) {
                                k3_=k2_; x3_=x2_; y3_=y2_; z3_=z2_;
                                if (key > k1_) {
                                    k2_=k1_; x2_=x1_; y2_=y1_; z2_=z1_;
                                    k1_=key; x1_=c.x; y1_=c.y; z1_=c.z;
                                } else { k2_=key; x2_=c.x; y2_=c.y; z2_=c.z; }
                            } else { k3_=key; x3_=c.x; y3_=c.y; z3_=c.z; }
                        } else { k4_=key; x4_=c.x; y4_=c.y; z4_=c.z; }
                    } else k5_ = key;
                }
            }
        }
        if (first && tid == 0) s_newN = n;

        // ---- per-wave sorted top-16 extraction (wave-private rows) ----
        int used = 0;
        for (int e = 0; e < 16; ++e) {
            u64 mk; float bx, by, bz;
            if      (used == 0) { mk=k1_; bx=x1_; by=y1_; bz=z1_; }
            else if (used == 1) { mk=k2_; bx=x2_; by=y2_; bz=z2_; }
            else if (used == 2) { mk=k3_; bx=x3_; by=y3_; bz=z3_; }
            else if (used == 3) { mk=k4_; bx=x4_; by=y4_; bz=z4_; }
            else                { mk=0;   bx=0.f; by=0.f; bz=0.f; }
            int src = lane;
            for (int off2 = 32; off2 > 0; off2 >>= 1) {
                u64 ok = __shfl_xor(mk, off2);
                int oi = __shfl_xor(src, off2);
                if (ok > mk) { mk = ok; src = oi; }
            }
            if (mk == 0) {   // wave exhausted: zero-fill rest, stop
                if (lane == 0) for (int e2 = e; e2 < 16; ++e2) sKey[wid][e2] = 0;
                break;
            }
            float wx = __shfl(bx, src), wy = __shfl(by, src), wz = __shfl(bz, src);
            if (lane == src) used++;
            if (lane == 0) { sKey[wid][e] = mk; sCtr[wid][e] = make_float4(wx,wy,wz,0.f); }
        }
        {   // horizon: best unconsumed key on this thread (k_{used+1})
            u64 mk;
            if      (used == 0) mk = k1_;
            else if (used == 1) mk = k2_;
            else if (used == 2) mk = k3_;
            else if (used == 3) mk = k4_;
            else                mk = k5_;
            for (int off2 = 32; off2 > 0; off2 >>= 1) {
                u64 ok = __shfl_xor(mk, off2);
                if (ok > mk) mk = ok;
            }
            if (lane == 0) atomicMax(&s_H, mk);
        }
        __syncthreads();

        int newN = s_newN;
        if (newN == 0) break;

        // ---- pop (wave 0): merge 16 sorted lists desc while key > H ----
        if (wid == 0) {
            u64 H = s_H;
            int head = (lane < 16) ? 0 : 16;
            float ax=0.f, ay=0.f, az=0.f; int agi = 0;
            int nacc = 0;
            while (nacc < 64) {
                u64 bk = (head < 16) ? sKey[lane][head] : 0;
                int src = lane;
                for (int off2 = 32; off2 > 0; off2 >>= 1) {
                    u64 ok = __shfl_xor(bk, off2);
                    int oi = __shfl_xor(src, off2);
                    if (ok > bk) { bk = ok; src = oi; }
                }
                if (bk <= H) break;
                int L = src;                       // uniform, < 16 since bk > 0
                int hL = __shfl(head, L);
                float4 w4 = sCtr[L][hL];
                u32 wgi = 0xFFFFFFFFu - (u32)(bk & 0xFFFFFFFFull);
                if (lane == L) head++;
                bool cov = false;
                if (lane < nacc) {
                    float dx = __fsub_rn(w4.x, ax);
                    float dy = __fsub_rn(w4.y, ay);
                    float dz = __fsub_rn(w4.z, az);
                    float dsq = __fadd_rn(__fadd_rn(__fmul_rn(dx,dx), __fmul_rn(dy,dy)),
                                          __fmul_rn(dz,dz));
                    cov = dsq < 0.09f;
                }
                if (__ballot(cov) == 0ull) {
                    if (lane == nacc) { ax=w4.x; ay=w4.y; az=w4.z; agi=(int)wgi; }
                    nacc++;
                }
            }
            if (lane < nacc && condTotal + lane < 1024) {
                ctr[condTotal + lane] = make_float4(ax, ay, az, 0.f);
                ctrGi[condTotal + lane] = agi;
            }
            if (lane == 0) s_nacc = nacc;
        }
        __syncthreads();

        prevStart = condTotal;
        condTotal += s_nacc;
        if (condTotal > 1024) condTotal = 1024;
        if (!first) {
            float4* t4 = cur; cur = nxt; nxt = t4;
            int* ti = icur; icur = inxt; inxt = ti;
        }
        n = newN;
        __syncthreads();   // everyone read s_nacc / lists before next-pass reset
        if (++passes > 300) break;   // safety (progress >= 1 pick/pass proven)
    }

    for (int i = tid; i < condTotal; i += 1024)
        condList[(size_t)s * CCAP + i] = ctrGi[i];
    if (tid == 0) condCount[s] = condTotal;
}

// Rank-sort each segment's pick list ascending, global sorted order,
// ncond cumulative counts as float32.
__global__ void finalize_kernel(const int* __restrict__ condList,
                                const int* __restrict__ condCount, int CCAP,
                                int* __restrict__ sorted, int* __restrict__ prefix,
                                float* __restrict__ ncond_out, int nseg, int rows) {
    __shared__ int lst[2048];
    __shared__ int pfx[9];
    int tid = threadIdx.x;
    if (tid == 0) {
        int acc = 0; pfx[0] = 0;
        for (int s2 = 0; s2 < nseg; s2++) { acc += condCount[s2]; pfx[s2 + 1] = acc; }
    }
    __syncthreads();
    if (tid <= nseg) { prefix[tid] = pfx[tid]; ncond_out[tid] = (float)pfx[tid]; }
    for (int s2 = 0; s2 < nseg; s2++) {
        int ns = condCount[s2]; if (ns > CCAP) ns = CCAP;
        for (int i = tid; i < ns; i += blockDim.x) lst[i] = condList[(size_t)s2 * CCAP + i];
        __syncthreads();
        for (int i = tid; i < ns; i += blockDim.x) {
            int v = lst[i]; int rank = 0;
            for (int j = 0; j < ns; j++) rank += (lst[j] < v);
            int pos = pfx[s2] + rank;
            if (pos < rows) sorted[pos] = v;
        }
        __syncthreads();
    }
}

__global__ void emit_kernel(const float* __restrict__ x, const int* __restrict__ sorted,
                            const int* __restrict__ prefix, float* __restrict__ out,
                            int rows, int nseg) {
    int e = blockIdx.x * blockDim.x + threadIdx.x;
    if (e >= rows * 17) return;
    int total = prefix[nseg];
    int j = e / 17, k = e - j * 17;
    float v = 0.f;
    if (j < total) v = x[(size_t)sorted[j] * 17 + k];
    out[e] = v;
}

extern "C" void kernel_launch(void* const* d_in, const int* in_sizes, int n_in,
                              void* d_out, int out_size, void* d_ws, size_t ws_size,
                              hipStream_t stream) {
    const float* x = (const float*)d_in[0];
    const int nseg = in_sizes[1] - 1;          // 4
    const int N = in_sizes[0] / 17;            // 1,000,000
    const int S = N / nseg;                    // 250,000
    const int rows = (out_size - (nseg + 1)) / 17;  // 1024 (MAX_COND)
    const int CCAP = 2048;

    const int bps = 1024 / nseg;               // blocks per segment (256)
    const int nBlocks = nseg * bps;            // 1024
    const int chunk = (S + bps - 1) / bps;     // 977 (< 1024 LDS staging cap)

    // workspace: [A][B] float4, [iA][iB], condList, segCount, condCount,
    // sorted, prefix
    char* w = (char*)d_ws;
    size_t fixedBytes = (size_t)nseg * CCAP * 4 + (size_t)nseg * 4 * 2 +
                        (size_t)rows * 4 + (size_t)(nseg + 1) * 4 + 4096;
    size_t perCand = (size_t)nseg * 2 * (16 + 4);
    size_t avail = (ws_size > fixedBytes) ? (ws_size - fixedBytes) : 0;
    int CAP = (int)(avail / perCand);
    if (CAP > 65536) CAP = 65536;
    if (CAP < 1) CAP = 1;

    float4* A  = (float4*)w;
    float4* Bb = A + (size_t)nseg * CAP;
    int* iA = (int*)(Bb + (size_t)nseg * CAP);
    int* iB = iA + (size_t)nseg * CAP;
    int* condList  = iB + (size_t)nseg * CAP;
    int* segCount  = condList + (size_t)nseg * CCAP;
    int* condCount = segCount + nseg;
    int* sorted    = condCount + nseg;
    int* prefix    = sorted + rows;
    float* out = (float*)d_out;

    init_kernel<<<1, 64, 0, stream>>>(segCount, condCount, nseg);
    filter_kernel<<<nBlocks, 256, 0, stream>>>(x, S, chunk, bps, segCount, A, iA, CAP);
    greedy_kernel<<<nseg, 1024, 0, stream>>>(A, iA, Bb, iB, segCount, CAP,
                                             condList, condCount, CCAP);
    finalize_kernel<<<1, 256, 0, stream>>>(condList, condCount, CCAP, sorted, prefix,
                                           out + (size_t)rows * 17, nseg, rows);
    emit_kernel<<<(rows * 17 + 255) / 256, 256, 0, stream>>>(x, sorted, prefix, out,
                                                             rows, nseg);
}

// Round 5
// 259.700 us; speedup vs baseline: 1.7060x; 1.5133x over previous
//
#include <hip/hip_runtime.h>
#include <stdint.h>

typedef unsigned long long u64;
typedef unsigned int u32;

// ---------------------------------------------------------------------------
// Constants: 17 feats/row, beta = col 9, cc = cols 14..16, T_B=0.85, T_D^2=0.09.
// Greedy condensation == scan candidates in descending (betaBits, ~idx) key
// order, accept iff not within T_D of any previously accepted center.
// R5: pop loop restructured so EVERY pop iteration commits one pick: pending
// top-4 (with coords) stays in thread registers; after each commit all 1024
// threads kill their own covered pending entries, so no coverage-rejected pop
// iterations remain (R4 burned 150-250 serial pops/pass on rejects). Horizon =
// block-max 5th-best key (binds ~rank 600 -> ~3 passes total).
// ---------------------------------------------------------------------------

__global__ void init_kernel(int* segCount, int* condCount, int nseg) {
    int t = threadIdx.x;
    if (t < nseg) { segCount[t] = 0; condCount[t] = 0; }
}

// Single-pass filter: block-local LDS staging, ONE global atomic per block.
__launch_bounds__(256)
__global__ void filter_kernel(const float* __restrict__ x, int S, int chunk, int bps,
                              int* __restrict__ segCount,
                              float4* __restrict__ A, int* __restrict__ iA, int CAP) {
    __shared__ float4 stg[1024];
    __shared__ int sgi[1024];
    __shared__ int s_cnt, s_base;
    int b = blockIdx.x;
    int s = b / bps, c = b % bps;
    int start = s * S + c * chunk;
    int end = min(start + chunk, s * S + S);
    if (threadIdx.x == 0) s_cnt = 0;
    __syncthreads();
    for (int i = start + threadIdx.x; i < end; i += 256) {
        float beta = x[(size_t)i * 17 + 9];
        if (beta >= 0.85f) {
            int p = atomicAdd(&s_cnt, 1);
            if (p < 1024) {
                stg[p] = make_float4(x[(size_t)i * 17 + 14], x[(size_t)i * 17 + 15],
                                     x[(size_t)i * 17 + 16], beta);
                sgi[p] = i;
            }
        }
    }
    __syncthreads();
    if (threadIdx.x == 0) s_base = atomicAdd(&segCount[s], min(s_cnt, 1024));
    __syncthreads();
    int cnt = min(s_cnt, 1024);
    for (int k = threadIdx.x; k < cnt; k += 256) {
        int pos = s_base + k;
        if (pos < CAP) {
            A[(size_t)s * CAP + pos] = stg[k];
            iA[(size_t)s * CAP + pos] = sgi[k];
        }
    }
}

// One block (1024 thr) per segment.
__launch_bounds__(1024)
__global__ void greedy_kernel(float4* __restrict__ A, int* __restrict__ iA,
                              float4* __restrict__ Bb, int* __restrict__ iB,
                              const int* __restrict__ candCount, int CAP,
                              int* __restrict__ condList, int* __restrict__ condCount,
                              int CCAP) {
    const int s = blockIdx.x;
    const int tid = threadIdx.x;
    const int lane = tid & 63;
    const int wid = tid >> 6;

    __shared__ u64 wkey[16];
    __shared__ float4 wctr[16];
    __shared__ float4 ctr[1024];
    __shared__ int ctrGi[1024];
    __shared__ u64 s_H, s_bestKey;
    __shared__ int s_newN;

    float4* cur = A + (size_t)s * CAP;
    int*    icur = iA + (size_t)s * CAP;
    float4* nxt = Bb + (size_t)s * CAP;
    int*    inxt = iB + (size_t)s * CAP;
    int n = candCount[s]; if (n > CAP) n = CAP;

    int condTotal = 0, prevStart = 0, passes = 0;

    while (true) {
        if (tid == 0) { s_H = 0; s_newN = 0; }
        __syncthreads();
        const bool first = (condTotal == 0);

        // ---- scan: coverage vs last pass's centers, compact, thread top-5 ----
        u64 k1=0,k2=0,k3=0,k4=0,k5=0;
        float x1=0,y1=0,z1=0,x2=0,y2=0,z2=0,
              x3=0,y3=0,z3=0,x4=0,y4=0,z4=0;
        for (int j = tid; j < n; j += 1024) {
            float4 c = cur[j];
            int g = icur[j];
            bool live = true;
            if (!first) {
                for (int m = prevStart; m < condTotal; ++m) {
                    float4 cc = ctr[m];   // uniform m -> LDS broadcast
                    float dx = __fsub_rn(c.x, cc.x);
                    float dy = __fsub_rn(c.y, cc.y);
                    float dz = __fsub_rn(c.z, cc.z);
                    float dsq = __fadd_rn(__fadd_rn(__fmul_rn(dx,dx), __fmul_rn(dy,dy)),
                                          __fmul_rn(dz,dz));
                    if (dsq < 0.09f) { live = false; break; }
                }
            }
            u64 bal = __ballot(live);
            if (live) {
                if (!first) {   // pass 1: everything survives, skip the copy
                    int leader = __ffsll((unsigned long long)bal) - 1;
                    int base = 0;
                    if (lane == leader) base = atomicAdd(&s_newN, __popcll(bal));
                    base = __shfl(base, leader);
                    int off = __popcll(bal & ((1ull << lane) - 1ull));
                    nxt[base + off] = c;
                    inxt[base + off] = g;
                }
                u64 key = ((u64)__float_as_uint(c.w) << 32) | (u64)(0xFFFFFFFFu - (u32)g);
                if (key > k5) {
                    if (key > k4) {
                        k5 = k4;
                        if (key > k3) {
                            k4=k3; x4=x3; y4=y3; z4=z3;
                            if (key > k2) {
                                k3=k2; x3=x2; y3=y2; z3=z2;
                                if (key > k1) {
                                    k2=k1; x2=x1; y2=y1; z2=z1;
                                    k1=key; x1=c.x; y1=c.y; z1=c.z;
                                } else { k2=key; x2=c.x; y2=c.y; z2=c.z; }
                            } else { k3=key; x3=c.x; y3=c.y; z3=c.z; }
                        } else { k4=key; x4=c.x; y4=c.y; z4=c.z; }
                    } else k5 = key;
                }
            }
        }
        if (first && tid == 0) s_newN = n;

        // ---- horizon: block max of per-thread 5th-best key ----
        u64 m5 = k5;
        for (int off = 32; off > 0; off >>= 1) {
            u64 o = __shfl_xor(m5, off);
            if (o > m5) m5 = o;
        }
        if (lane == 0) atomicMax(&s_H, m5);
        __syncthreads();
        int newN = s_newN;
        if (newN == 0) break;         // everything covered: done
        u64 H = s_H;

        prevStart = condTotal;        // centers committed THIS pass start here

        // ---- pop: every iteration commits exactly one greedy pick ----
        while (condTotal < 1024) {
            u64 mk = k1;
            if (k2 > mk) mk = k2;
            if (k3 > mk) mk = k3;
            if (k4 > mk) mk = k4;
            u64 wm = mk;
            for (int off = 32; off > 0; off >>= 1) {
                u64 o = __shfl_xor(wm, off);
                if (o > wm) wm = o;
            }
            if (lane == 0) wkey[wid] = wm;
            if (wm != 0 && mk == wm) {          // unique winner lane (keys unique)
                float4 cc;
                if      (mk == k1) cc = make_float4(x1, y1, z1, 0.f);
                else if (mk == k2) cc = make_float4(x2, y2, z2, 0.f);
                else if (mk == k3) cc = make_float4(x3, y3, z3, 0.f);
                else               cc = make_float4(x4, y4, z4, 0.f);
                wctr[wid] = cc;
            }
            __syncthreads();
            if (wid == 0) {
                u64 bk = (lane < 16) ? wkey[lane] : 0;
                u64 bm = bk;
                for (int off = 32; off > 0; off >>= 1) {
                    u64 o = __shfl_xor(bm, off);
                    if (o > bm) bm = o;
                }
                if (lane == 0) s_bestKey = bm;
                if (lane < 16 && bm != 0 && bk == bm) {   // unique winner wave
                    ctr[condTotal] = wctr[lane];
                    ctrGi[condTotal] = (int)(0xFFFFFFFFu - (u32)(bm & 0xFFFFFFFFull));
                }
            }
            __syncthreads();
            u64 bk = s_bestKey;
            if (bk <= H) break;       // remaining picks hidden below horizon
            float4 c = ctr[condTotal];
            if (k1) { float dx=__fsub_rn(x1,c.x),dy=__fsub_rn(y1,c.y),dz=__fsub_rn(z1,c.z);
                if (__fadd_rn(__fadd_rn(__fmul_rn(dx,dx),__fmul_rn(dy,dy)),__fmul_rn(dz,dz)) < 0.09f) k1=0; }
            if (k2) { float dx=__fsub_rn(x2,c.x),dy=__fsub_rn(y2,c.y),dz=__fsub_rn(z2,c.z);
                if (__fadd_rn(__fadd_rn(__fmul_rn(dx,dx),__fmul_rn(dy,dy)),__fmul_rn(dz,dz)) < 0.09f) k2=0; }
            if (k3) { float dx=__fsub_rn(x3,c.x),dy=__fsub_rn(y3,c.y),dz=__fsub_rn(z3,c.z);
                if (__fadd_rn(__fadd_rn(__fmul_rn(dx,dx),__fmul_rn(dy,dy)),__fmul_rn(dz,dz)) < 0.09f) k3=0; }
            if (k4) { float dx=__fsub_rn(x4,c.x),dy=__fsub_rn(y4,c.y),dz=__fsub_rn(z4,c.z);
                if (__fadd_rn(__fadd_rn(__fmul_rn(dx,dx),__fmul_rn(dy,dy)),__fmul_rn(dz,dz)) < 0.09f) k4=0; }
            condTotal++;               // all threads agree
        }

        if (!first) {
            float4* t4 = cur; cur = nxt; nxt = t4;
            int* ti = icur; icur = inxt; inxt = ti;
        }
        n = newN;
        __syncthreads();
        if (condTotal >= 1024 || ++passes > 300) break;   // safety
    }

    for (int i = tid; i < condTotal; i += 1024)
        condList[(size_t)s * CCAP + i] = ctrGi[i];
    if (tid == 0) condCount[s] = condTotal;
}

// Rank-sort each segment's pick list ascending, global sorted order,
// ncond cumulative counts as float32.
__global__ void finalize_kernel(const int* __restrict__ condList,
                                const int* __restrict__ condCount, int CCAP,
                                int* __restrict__ sorted, int* __restrict__ prefix,
                                float* __restrict__ ncond_out, int nseg, int rows) {
    __shared__ int lst[2048];
    __shared__ int pfx[9];
    int tid = threadIdx.x;
    if (tid == 0) {
        int acc = 0; pfx[0] = 0;
        for (int s2 = 0; s2 < nseg; s2++) { acc += condCount[s2]; pfx[s2 + 1] = acc; }
    }
    __syncthreads();
    if (tid <= nseg) { prefix[tid] = pfx[tid]; ncond_out[tid] = (float)pfx[tid]; }
    for (int s2 = 0; s2 < nseg; s2++) {
        int ns = condCount[s2]; if (ns > CCAP) ns = CCAP;
        for (int i = tid; i < ns; i += blockDim.x) lst[i] = condList[(size_t)s2 * CCAP + i];
        __syncthreads();
        for (int i = tid; i < ns; i += blockDim.x) {
            int v = lst[i]; int rank = 0;
            for (int j = 0; j < ns; j++) rank += (lst[j] < v);
            int pos = pfx[s2] + rank;
            if (pos < rows) sorted[pos] = v;
        }
        __syncthreads();
    }
}

__global__ void emit_kernel(const float* __restrict__ x, const int* __restrict__ sorted,
                            const int* __restrict__ prefix, float* __restrict__ out,
                            int rows, int nseg) {
    int e = blockIdx.x * blockDim.x + threadIdx.x;
    if (e >= rows * 17) return;
    int total = prefix[nseg];
    int j = e / 17, k = e - j * 17;
    float v = 0.f;
    if (j < total) v = x[(size_t)sorted[j] * 17 + k];
    out[e] = v;
}

extern "C" void kernel_launch(void* const* d_in, const int* in_sizes, int n_in,
                              void* d_out, int out_size, void* d_ws, size_t ws_size,
                              hipStream_t stream) {
    const float* x = (const float*)d_in[0];
    const int nseg = in_sizes[1] - 1;          // 4
    const int N = in_sizes[0] / 17;            // 1,000,000
    const int S = N / nseg;                    // 250,000
    const int rows = (out_size - (nseg + 1)) / 17;  // 1024 (MAX_COND)
    const int CCAP = 2048;

    const int bps = 1024 / nseg;               // blocks per segment (256)
    const int nBlocks = nseg * bps;            // 1024
    const int chunk = (S + bps - 1) / bps;     // 977 (< 1024 LDS staging cap)

    char* w = (char*)d_ws;
    size_t fixedBytes = (size_t)nseg * CCAP * 4 + (size_t)nseg * 4 * 2 +
                        (size_t)rows * 4 + (size_t)(nseg + 1) * 4 + 4096;
    size_t perCand = (size_t)nseg * 2 * (16 + 4);
    size_t avail = (ws_size > fixedBytes) ? (ws_size - fixedBytes) : 0;
    int CAP = (int)(avail / perCand);
    if (CAP > 65536) CAP = 65536;
    if (CAP < 1) CAP = 1;

    float4* A  = (float4*)w;
    float4* Bb = A + (size_t)nseg * CAP;
    int* iA = (int*)(Bb + (size_t)nseg * CAP);
    int* iB = iA + (size_t)nseg * CAP;
    int* condList  = iB + (size_t)nseg * CAP;
    int* segCount  = condList + (size_t)nseg * CCAP;
    int* condCount = segCount + nseg;
    int* sorted    = condCount + nseg;
    int* prefix    = sorted + rows;
    float* out = (float*)d_out;

    init_kernel<<<1, 64, 0, stream>>>(segCount, condCount, nseg);
    filter_kernel<<<nBlocks, 256, 0, stream>>>(x, S, chunk, bps, segCount, A, iA, CAP);
    greedy_kernel<<<nseg, 1024, 0, stream>>>(A, iA, Bb, iB, segCount, CAP,
                                             condList, condCount, CCAP);
    finalize_kernel<<<1, 256, 0, stream>>>(condList, condCount, CCAP, sorted, prefix,
                                           out + (size_t)rows * 17, nseg, rows);
    emit_kernel<<<(rows * 17 + 255) / 256, 256, 0, stream>>>(x, sorted, prefix, out,
                                                             rows, nseg);
}